// Round 1
// baseline (128.347 us; speedup 1.0000x reference)
//
#include <hip/hip_runtime.h>
#include <hip/hip_bf16.h>
#include <stdint.h>

#define Bn 8
#define Sn 2048
#define Hn 768
#define Rn 768
#define Mn (Bn*Sn)          // 16384
#define BK 32

typedef __attribute__((ext_vector_type(8))) __bf16 bf16x8;
typedef __attribute__((ext_vector_type(4))) float f32x4;

__device__ __forceinline__ void gload_lds16(const void* g, void* l) {
    __builtin_amdgcn_global_load_lds(
        (const __attribute__((address_space(1))) uint32_t*)g,
        (__attribute__((address_space(3))) uint32_t*)l,
        16, 0, 0);
}

__device__ __forceinline__ unsigned short f2bf_bits(float f) {
    // RTNE bf16 (inputs are finite/normal-scale; NaN path not needed)
    uint32_t u = __builtin_bit_cast(uint32_t, f);
    u += 0x7fffu + ((u >> 16) & 1u);
    return (unsigned short)(u >> 16);
}

// ---------------- convert batch f32 -> bf16 (vectorized) ----------------
__global__ void cvt_batch(const float4* __restrict__ in, ushort4* __restrict__ out, int n4) {
    int i = blockIdx.x * blockDim.x + threadIdx.x;
    int stride = gridDim.x * blockDim.x;
    for (; i < n4; i += stride) {
        float4 v = in[i];
        ushort4 o;
        o.x = f2bf_bits(v.x);
        o.y = f2bf_bits(v.y);
        o.z = f2bf_bits(v.z);
        o.w = f2bf_bits(v.w);
        out[i] = o;
    }
}

// ---------------- convert + transpose proj: projT[r][h] = bf16(proj[h][r]) ----------------
// Coalesced writes; reads scattered but proj is 2.4 MB (cache-resident).
__global__ void cvt_projT(const float* __restrict__ proj, __hip_bfloat16* __restrict__ projT) {
    int t = blockIdx.x * blockDim.x + threadIdx.x;
    if (t < Hn * Rn) {
        int r = t / Hn;
        int h = t - r * Hn;
        projT[t] = __hip_bfloat16(__builtin_bit_cast(__hip_bfloat16_raw, f2bf_bits(proj[h * Rn + r])));
    }
}

// ---------------- projection GEMM: t[M][R] = A[M][H] * projT[R][H]^T ----------------
// m97-style: 128x128 tile, BK=32, 4 waves (2x2), 4x4 16x16x32 frags per wave.
__global__ __launch_bounds__(256, 2)
void gemm_proj(const __hip_bfloat16* __restrict__ A,   // [Mn][Hn]
               const __hip_bfloat16* __restrict__ Bt,  // [Rn][Hn]
               __hip_bfloat16* __restrict__ Ct) {      // [Mn][Rn]
    __shared__ __hip_bfloat16 As[128 * BK];
    __shared__ __hip_bfloat16 Bs[128 * BK];
    const int tid  = threadIdx.x;
    const int lane = tid & 63;
    const int w    = tid >> 6;
    const int wr   = w >> 1, wc = w & 1;          // 2x2 wave grid, 64x64 each
    const int row0 = blockIdx.x * 128;            // Mn/128 = 128
    const int col0 = blockIdx.y * 128;            // Rn/128 = 6

    f32x4 acc[4][4];
#pragma unroll
    for (int i = 0; i < 4; ++i)
#pragma unroll
        for (int j = 0; j < 4; ++j) acc[i][j] = (f32x4){0.f, 0.f, 0.f, 0.f};

    const int kk = (lane >> 4) * 8;   // k offset within 32
    const int rA = lane & 15;

    for (int k0 = 0; k0 < Hn; k0 += BK) {
        // stage A,B tiles: 128x32 bf16 each = 8 KB; 512 16B chunks; 2 per thread
#pragma unroll
        for (int i = 0; i < 2; ++i) {
            int c16 = tid + i * 256;
            int r = c16 >> 2;
            int c = (c16 & 3) * 8;
            gload_lds16(A  + (size_t)(row0 + r) * Hn + k0 + c, As + c16 * 8);
            gload_lds16(Bt + (size_t)(col0 + r) * Hn + k0 + c, Bs + c16 * 8);
        }
        __syncthreads();   // compiler emits vmcnt(0) drain before barrier

        bf16x8 af[4], bfr[4];
#pragma unroll
        for (int f = 0; f < 4; ++f) {
            af[f]  = *(const bf16x8*)(As + (wr * 64 + f * 16 + rA) * BK + kk);
            bfr[f] = *(const bf16x8*)(Bs + (wc * 64 + f * 16 + rA) * BK + kk);
        }
#pragma unroll
        for (int fm = 0; fm < 4; ++fm)
#pragma unroll
            for (int fn = 0; fn < 4; ++fn)
                acc[fm][fn] = __builtin_amdgcn_mfma_f32_16x16x32_bf16(af[fm], bfr[fn], acc[fm][fn], 0, 0, 0);
        __syncthreads();
    }

    // epilogue: C/D layout col=lane&15, row=(lane>>4)*4+reg
    const int cr = (lane >> 4) * 4;
    const int cc = lane & 15;
#pragma unroll
    for (int fm = 0; fm < 4; ++fm)
#pragma unroll
        for (int fn = 0; fn < 4; ++fn)
#pragma unroll
            for (int j = 0; j < 4; ++j) {
                int row = row0 + wr * 64 + fm * 16 + cr + j;
                int col = col0 + wc * 64 + fn * 16 + cc;
                Ct[(size_t)row * Rn + col] =
                    __hip_bfloat16(__builtin_bit_cast(__hip_bfloat16_raw, f2bf_bits(acc[fm][fn][j])));
            }
}

// ---------------- sq[i] = sum_r t[i][r]^2 (one wave per row) ----------------
__global__ __launch_bounds__(256)
void sq_kernel(const __hip_bfloat16* __restrict__ T, float* __restrict__ sq) {
    int row  = blockIdx.x * 4 + (threadIdx.x >> 6);
    int lane = threadIdx.x & 63;
    const uint32_t* p = (const uint32_t*)(T + (size_t)row * Rn);  // 384 u32
    float s = 0.f;
#pragma unroll
    for (int i = 0; i < 6; ++i) {
        uint32_t u = p[lane + i * 64];
        float lo = __builtin_bit_cast(float, u << 16);
        float hi = __builtin_bit_cast(float, u & 0xffff0000u);
        s = fmaf(lo, lo, s);
        s = fmaf(hi, hi, s);
    }
#pragma unroll
    for (int off = 32; off > 0; off >>= 1) s += __shfl_xor(s, off, 64);
    if (lane == 0) sq[row] = s;
}

// ---------------- gram + epilogue: out[b][i][j] = max(sq_i + sq_j - 2*t_i.t_j, 0) ----------------
__global__ __launch_bounds__(256, 2)
void gram(const __hip_bfloat16* __restrict__ T, const float* __restrict__ sq,
          float* __restrict__ out) {
    __shared__ __hip_bfloat16 As[128 * BK];
    __shared__ __hip_bfloat16 Bs[128 * BK];
    const int tid  = threadIdx.x;
    const int lane = tid & 63;
    const int w    = tid >> 6;
    const int wr   = w >> 1, wc = w & 1;
    const int b    = blockIdx.z;
    const __hip_bfloat16* Tb = T + (size_t)b * Sn * Rn;
    const float* sqb = sq + b * Sn;
    float* outb = out + (size_t)b * Sn * Sn;
    const int row0 = blockIdx.y * 128;   // 16 tiles
    const int col0 = blockIdx.x * 128;   // 16 tiles

    f32x4 acc[4][4];
#pragma unroll
    for (int i = 0; i < 4; ++i)
#pragma unroll
        for (int j = 0; j < 4; ++j) acc[i][j] = (f32x4){0.f, 0.f, 0.f, 0.f};

    const int kk = (lane >> 4) * 8;
    const int rA = lane & 15;

    for (int k0 = 0; k0 < Rn; k0 += BK) {
#pragma unroll
        for (int i = 0; i < 2; ++i) {
            int c16 = tid + i * 256;
            int r = c16 >> 2;
            int c = (c16 & 3) * 8;
            gload_lds16(Tb + (size_t)(row0 + r) * Rn + k0 + c, As + c16 * 8);
            gload_lds16(Tb + (size_t)(col0 + r) * Rn + k0 + c, Bs + c16 * 8);
        }
        __syncthreads();

        bf16x8 af[4], bfr[4];
#pragma unroll
        for (int f = 0; f < 4; ++f) {
            af[f]  = *(const bf16x8*)(As + (wr * 64 + f * 16 + rA) * BK + kk);
            bfr[f] = *(const bf16x8*)(Bs + (wc * 64 + f * 16 + rA) * BK + kk);
        }
#pragma unroll
        for (int fm = 0; fm < 4; ++fm)
#pragma unroll
            for (int fn = 0; fn < 4; ++fn)
                acc[fm][fn] = __builtin_amdgcn_mfma_f32_16x16x32_bf16(af[fm], bfr[fn], acc[fm][fn], 0, 0, 0);
        __syncthreads();
    }

    const int cr = (lane >> 4) * 4;
    const int cc = lane & 15;
#pragma unroll
    for (int fm = 0; fm < 4; ++fm)
#pragma unroll
        for (int fn = 0; fn < 4; ++fn) {
            int col = col0 + wc * 64 + fn * 16 + cc;
            float sqc = sqb[col];
#pragma unroll
            for (int j = 0; j < 4; ++j) {
                int row = row0 + wr * 64 + fm * 16 + cr + j;
                float v = sqb[row] + sqc - 2.0f * acc[fm][fn][j];
                outb[(size_t)row * Sn + col] = fmaxf(v, 0.0f);
            }
        }
}

extern "C" void kernel_launch(void* const* d_in, const int* in_sizes, int n_in,
                              void* d_out, int out_size, void* d_ws, size_t ws_size,
                              hipStream_t stream) {
    const float* batch = (const float*)d_in[0];   // [8][2048][768] f32
    const float* proj  = (const float*)d_in[1];   // [768][768] f32
    float* out = (float*)d_out;                   // [8][2048][2048] f32

    char* ws = (char*)d_ws;
    __hip_bfloat16* batch_bf = (__hip_bfloat16*)(ws);                    // 25,165,824 B
    __hip_bfloat16* projT    = (__hip_bfloat16*)(ws + 25165824);         //  1,179,648 B
    __hip_bfloat16* t_bf     = (__hip_bfloat16*)(ws + 26345472);         // 25,165,824 B
    float*          sqv      = (float*)(ws + 51511296);                  //     65,536 B

    int n4 = (Mn * Hn) / 4;   // 3,145,728
    cvt_batch<<<2048, 256, 0, stream>>>((const float4*)batch, (ushort4*)batch_bf, n4);
    cvt_projT<<<(Hn * Rn + 255) / 256, 256, 0, stream>>>(proj, projT);
    gemm_proj<<<dim3(Mn / 128, Rn / 128), 256, 0, stream>>>(batch_bf, projT, t_bf);
    sq_kernel<<<Mn / 4, 256, 0, stream>>>(t_bf, sqv);
    gram<<<dim3(Sn / 128, Sn / 128, Bn), 256, 0, stream>>>(t_bf, sqv, out);
}

// Round 2
// 110.220 us; speedup vs baseline: 1.1645x; 1.1645x over previous
//
#include <hip/hip_runtime.h>
#include <hip/hip_bf16.h>
#include <stdint.h>

#define Bn 8
#define Sn 2048
#define Hn 768
#define Rn 768
#define Mn (Bn*Sn)          // 16384
#define BK 32

typedef __attribute__((ext_vector_type(8))) __bf16 bf16x8;
typedef __attribute__((ext_vector_type(4))) float f32x4;

__device__ __forceinline__ void gload_lds16(const void* g, void* l) {
    __builtin_amdgcn_global_load_lds(
        (const __attribute__((address_space(1))) uint32_t*)g,
        (__attribute__((address_space(3))) uint32_t*)l,
        16, 0, 0);
}

__device__ __forceinline__ unsigned short f2bf_bits(float f) {
    uint32_t u = __builtin_bit_cast(uint32_t, f);
    u += 0x7fffu + ((u >> 16) & 1u);
    return (unsigned short)(u >> 16);
}

// ---------------- convert batch f32 -> bf16 (vectorized) ----------------
__global__ void cvt_batch(const float4* __restrict__ in, ushort4* __restrict__ out, int n4) {
    int i = blockIdx.x * blockDim.x + threadIdx.x;
    int stride = gridDim.x * blockDim.x;
    for (; i < n4; i += stride) {
        float4 v = in[i];
        ushort4 o;
        o.x = f2bf_bits(v.x);
        o.y = f2bf_bits(v.y);
        o.z = f2bf_bits(v.z);
        o.w = f2bf_bits(v.w);
        out[i] = o;
    }
}

// ---------------- convert + transpose proj: projT[r][h] = bf16(proj[h][r]) ----------------
__global__ void cvt_projT(const float* __restrict__ proj, __hip_bfloat16* __restrict__ projT) {
    int t = blockIdx.x * blockDim.x + threadIdx.x;
    if (t < Hn * Rn) {
        int r = t / Hn;
        int h = t - r * Hn;
        projT[t] = __hip_bfloat16(__builtin_bit_cast(__hip_bfloat16_raw, f2bf_bits(proj[h * Rn + r])));
    }
}

// ---------------- projection GEMM: t[M][R] = A[M][H] * projT[R][H]^T ----------------
__global__ __launch_bounds__(256, 2)
void gemm_proj(const __hip_bfloat16* __restrict__ A,   // [Mn][Hn]
               const __hip_bfloat16* __restrict__ Bt,  // [Rn][Hn]
               __hip_bfloat16* __restrict__ Ct) {      // [Mn][Rn]
    __shared__ __hip_bfloat16 As[128 * BK];
    __shared__ __hip_bfloat16 Bs[128 * BK];
    const int tid  = threadIdx.x;
    const int lane = tid & 63;
    const int w    = tid >> 6;
    const int wr   = w >> 1, wc = w & 1;
    const int row0 = blockIdx.x * 128;
    const int col0 = blockIdx.y * 128;

    f32x4 acc[4][4];
#pragma unroll
    for (int i = 0; i < 4; ++i)
#pragma unroll
        for (int j = 0; j < 4; ++j) acc[i][j] = (f32x4){0.f, 0.f, 0.f, 0.f};

    const int kk = (lane >> 4) * 8;
    const int rA = lane & 15;

    for (int k0 = 0; k0 < Hn; k0 += BK) {
#pragma unroll
        for (int i = 0; i < 2; ++i) {
            int c16 = tid + i * 256;
            int r = c16 >> 2;
            int c = (c16 & 3) * 8;
            gload_lds16(A  + (size_t)(row0 + r) * Hn + k0 + c, As + c16 * 8);
            gload_lds16(Bt + (size_t)(col0 + r) * Hn + k0 + c, Bs + c16 * 8);
        }
        __syncthreads();

        bf16x8 af[4], bfr[4];
#pragma unroll
        for (int f = 0; f < 4; ++f) {
            af[f]  = *(const bf16x8*)(As + (wr * 64 + f * 16 + rA) * BK + kk);
            bfr[f] = *(const bf16x8*)(Bs + (wc * 64 + f * 16 + rA) * BK + kk);
        }
#pragma unroll
        for (int fm = 0; fm < 4; ++fm)
#pragma unroll
            for (int fn = 0; fn < 4; ++fn)
                acc[fm][fn] = __builtin_amdgcn_mfma_f32_16x16x32_bf16(af[fm], bfr[fn], acc[fm][fn], 0, 0, 0);
        __syncthreads();
    }

    const int cr = (lane >> 4) * 4;
    const int cc = lane & 15;
#pragma unroll
    for (int fm = 0; fm < 4; ++fm)
#pragma unroll
        for (int fn = 0; fn < 4; ++fn)
#pragma unroll
            for (int j = 0; j < 4; ++j) {
                int row = row0 + wr * 64 + fm * 16 + cr + j;
                int col = col0 + wc * 64 + fn * 16 + cc;
                Ct[(size_t)row * Rn + col] =
                    __hip_bfloat16(__builtin_bit_cast(__hip_bfloat16_raw, f2bf_bits(acc[fm][fn][j])));
            }
}

// ---------------- sq[i] = sum_r t[i][r]^2 (one wave per row) ----------------
__global__ __launch_bounds__(256)
void sq_kernel(const __hip_bfloat16* __restrict__ T, float* __restrict__ sq) {
    int row  = blockIdx.x * 4 + (threadIdx.x >> 6);
    int lane = threadIdx.x & 63;
    const uint32_t* p = (const uint32_t*)(T + (size_t)row * Rn);
    float s = 0.f;
#pragma unroll
    for (int i = 0; i < 6; ++i) {
        uint32_t u = p[lane + i * 64];
        float lo = __builtin_bit_cast(float, u << 16);
        float hi = __builtin_bit_cast(float, u & 0xffff0000u);
        s = fmaf(lo, lo, s);
        s = fmaf(hi, hi, s);
    }
#pragma unroll
    for (int off = 32; off > 0; off >>= 1) s += __shfl_xor(s, off, 64);
    if (lane == 0) sq[row] = s;
}

// ---------------- symmetric gram: only upper-triangular tiles; mirror via LDS transpose ----------------
// grid = 8 batches * 136 upper-tri tiles = 1088 linear blocks.
// b = blockIdx.x % 8  -> pins each batch to one XCD (t_b = 3 MB fits its 4 MB L2).
__global__ __launch_bounds__(256, 2)
void gram_sym(const __hip_bfloat16* __restrict__ T, const float* __restrict__ sq,
              float* __restrict__ out) {
    __shared__ __hip_bfloat16 As[128 * BK];
    __shared__ __hip_bfloat16 Bs[128 * BK];
    __shared__ float tsc[4][16 * 20];   // per-wave transpose scratch, row stride 20 (16B-aligned rows, bank-spread)

    const int tid  = threadIdx.x;
    const int lane = tid & 63;
    const int w    = tid >> 6;
    const int wr   = w >> 1, wc = w & 1;

    const int L = blockIdx.x;
    const int b = L & 7;
    int tile_id = L >> 3;               // 0..135
    int ty = 0;
    {
        int rowlen = 16;
        while (tile_id >= rowlen) { tile_id -= rowlen; --rowlen; ++ty; }
    }
    const int tx = ty + tile_id;
    const bool diag = (ty == tx);
    const int row0 = ty * 128;
    const int col0 = tx * 128;

    const __hip_bfloat16* Tb = T + (size_t)b * Sn * Rn;
    const float* sqb = sq + b * Sn;
    float* outb = out + (size_t)b * Sn * Sn;

    f32x4 acc[4][4];
#pragma unroll
    for (int i = 0; i < 4; ++i)
#pragma unroll
        for (int j = 0; j < 4; ++j) acc[i][j] = (f32x4){0.f, 0.f, 0.f, 0.f};

    const int kk = (lane >> 4) * 8;
    const int rA = lane & 15;

    for (int k0 = 0; k0 < Rn; k0 += BK) {
#pragma unroll
        for (int i = 0; i < 2; ++i) {
            int c16 = tid + i * 256;
            int r = c16 >> 2;
            int c = (c16 & 3) * 8;
            gload_lds16(Tb + (size_t)(row0 + r) * Rn + k0 + c, As + c16 * 8);
            if (!diag)
                gload_lds16(Tb + (size_t)(col0 + r) * Rn + k0 + c, Bs + c16 * 8);
        }
        __syncthreads();

        const __hip_bfloat16* Bsrc = diag ? As : Bs;
        bf16x8 af[4], bfr[4];
#pragma unroll
        for (int f = 0; f < 4; ++f) {
            af[f]  = *(const bf16x8*)(As   + (wr * 64 + f * 16 + rA) * BK + kk);
            bfr[f] = *(const bf16x8*)(Bsrc + (wc * 64 + f * 16 + rA) * BK + kk);
        }
#pragma unroll
        for (int fm = 0; fm < 4; ++fm)
#pragma unroll
            for (int fn = 0; fn < 4; ++fn)
                acc[fm][fn] = __builtin_amdgcn_mfma_f32_16x16x32_bf16(af[fm], bfr[fn], acc[fm][fn], 0, 0, 0);
        __syncthreads();
    }

    const int cr = (lane >> 4) * 4;
    const int cc = lane & 15;
    float* sc = tsc[w];

#pragma unroll
    for (int fm = 0; fm < 4; ++fm)
#pragma unroll
        for (int fn = 0; fn < 4; ++fn) {
            const int col = col0 + wc * 64 + fn * 16 + cc;
            const float sqc = sqb[col];
            float v[4];
#pragma unroll
            for (int j = 0; j < 4; ++j) {
                const int row = row0 + wr * 64 + fm * 16 + cr + j;
                v[j] = fmaxf(sqb[row] + sqc - 2.0f * acc[fm][fn][j], 0.0f);
                outb[(size_t)row * Sn + col] = v[j];
            }
            if (!diag) {
                // transpose fragment via per-wave LDS scratch: F(r,c) -> sc[r*20+c]
#pragma unroll
                for (int j = 0; j < 4; ++j) sc[(cr + j) * 20 + cc] = v[j];
                // lane reads T(r'=cr+j, c'=cc) = F(cc, cr+j); 4 consecutive -> float4 (16B aligned: 20*4B rows)
                float4 tv = *(const float4*)(sc + cc * 20 + cr);
#pragma unroll
                for (int j = 0; j < 4; ++j) {
                    const int mrow = col0 + wc * 64 + fn * 16 + cr + j;
                    const int mcol = row0 + wr * 64 + fm * 16 + cc;
                    outb[(size_t)mrow * Sn + mcol] = ((const float*)&tv)[j];
                }
            }
        }
}

extern "C" void kernel_launch(void* const* d_in, const int* in_sizes, int n_in,
                              void* d_out, int out_size, void* d_ws, size_t ws_size,
                              hipStream_t stream) {
    const float* batch = (const float*)d_in[0];   // [8][2048][768] f32
    const float* proj  = (const float*)d_in[1];   // [768][768] f32
    float* out = (float*)d_out;                   // [8][2048][2048] f32

    char* ws = (char*)d_ws;
    __hip_bfloat16* batch_bf = (__hip_bfloat16*)(ws);                    // 25,165,824 B
    __hip_bfloat16* projT    = (__hip_bfloat16*)(ws + 25165824);         //  1,179,648 B
    __hip_bfloat16* t_bf     = (__hip_bfloat16*)(ws + 26345472);         // 25,165,824 B
    float*          sqv      = (float*)(ws + 51511296);                  //     65,536 B

    int n4 = (Mn * Hn) / 4;
    cvt_batch<<<2048, 256, 0, stream>>>((const float4*)batch, (ushort4*)batch_bf, n4);
    cvt_projT<<<(Hn * Rn + 255) / 256, 256, 0, stream>>>(proj, projT);
    gemm_proj<<<dim3(Mn / 128, Rn / 128), 256, 0, stream>>>(batch_bf, projT, t_bf);
    sq_kernel<<<Mn / 4, 256, 0, stream>>>(t_bf, sqv);
    gram_sym<<<8 * 136, 256, 0, stream>>>(t_bf, sqv, out);
}

// Round 3
// 102.599 us; speedup vs baseline: 1.2510x; 1.0743x over previous
//
#include <hip/hip_runtime.h>
#include <hip/hip_bf16.h>
#include <stdint.h>

#define Bn 8
#define Sn 2048
#define Hn 768
#define Rn 768
#define Mn (Bn*Sn)          // 16384

typedef __attribute__((ext_vector_type(8))) __bf16 bf16x8;
typedef __attribute__((ext_vector_type(4))) float f32x4;

__device__ __forceinline__ void gload_lds16(const void* g, void* l) {
    __builtin_amdgcn_global_load_lds(
        (const __attribute__((address_space(1))) uint32_t*)g,
        (__attribute__((address_space(3))) uint32_t*)l,
        16, 0, 0);
}

__device__ __forceinline__ unsigned short f2bf_bits(float f) {
    uint32_t u = __builtin_bit_cast(uint32_t, f);
    u += 0x7fffu + ((u >> 16) & 1u);
    return (unsigned short)(u >> 16);
}

// ---------------- convert batch f32 -> bf16 (vectorized) ----------------
__global__ void cvt_batch(const float4* __restrict__ in, ushort4* __restrict__ out, int n4) {
    int i = blockIdx.x * blockDim.x + threadIdx.x;
    int stride = gridDim.x * blockDim.x;
    for (; i < n4; i += stride) {
        float4 v = in[i];
        ushort4 o;
        o.x = f2bf_bits(v.x);
        o.y = f2bf_bits(v.y);
        o.z = f2bf_bits(v.z);
        o.w = f2bf_bits(v.w);
        out[i] = o;
    }
}

// ---------------- convert + transpose proj: projT[r][h] = bf16(proj[h][r]) ----------------
__global__ void cvt_projT(const float* __restrict__ proj, __hip_bfloat16* __restrict__ projT) {
    int t = blockIdx.x * blockDim.x + threadIdx.x;
    if (t < Hn * Rn) {
        int r = t / Hn;
        int h = t - r * Hn;
        projT[t] = __hip_bfloat16(__builtin_bit_cast(__hip_bfloat16_raw, f2bf_bits(proj[h * Rn + r])));
    }
}

// ---------------- projection GEMM: t[M][R] = A[M][H] * projT[R][H]^T ----------------
// m97 structure, BK=32; LDS chunk swizzle: slot c holds logical chunk c ^ ((row>>1)&3).
// Staging pre-swizzles the GLOBAL source (rule 21: linear gload_lds dest + inv-swz src + swz read).
#define BKP 32
__global__ __launch_bounds__(256, 4)
void gemm_proj(const __hip_bfloat16* __restrict__ A,   // [Mn][Hn]
               const __hip_bfloat16* __restrict__ Bt,  // [Rn][Hn]
               __hip_bfloat16* __restrict__ Ct) {      // [Mn][Rn]
    __shared__ __hip_bfloat16 As[128 * BKP];
    __shared__ __hip_bfloat16 Bs[128 * BKP];
    const int tid  = threadIdx.x;
    const int lane = tid & 63;
    const int w    = tid >> 6;
    const int wr   = w >> 1, wc = w & 1;
    const int row0 = blockIdx.x * 128;
    const int col0 = blockIdx.y * 128;

    f32x4 acc[4][4];
#pragma unroll
    for (int i = 0; i < 4; ++i)
#pragma unroll
        for (int j = 0; j < 4; ++j) acc[i][j] = (f32x4){0.f, 0.f, 0.f, 0.f};

    const int cl = lane >> 4;     // logical 16B chunk (k/8)
    const int rA = lane & 15;

    for (int k0 = 0; k0 < Hn; k0 += BKP) {
#pragma unroll
        for (int i = 0; i < 2; ++i) {
            int c16 = tid + i * 256;        // chunk id 0..511
            int r = c16 >> 2;               // row 0..127
            int c = c16 & 3;                // LDS slot
            int csrc = c ^ ((r >> 1) & 3);  // logical chunk that lives at slot c
            gload_lds16(A  + (size_t)(row0 + r) * Hn + k0 + csrc * 8, As + c16 * 8);
            gload_lds16(Bt + (size_t)(col0 + r) * Hn + k0 + csrc * 8, Bs + c16 * 8);
        }
        __syncthreads();

        bf16x8 af[4], bfr[4];
#pragma unroll
        for (int f = 0; f < 4; ++f) {
            int ra = wr * 64 + f * 16 + rA;
            int rb = wc * 64 + f * 16 + rA;
            af[f]  = *(const bf16x8*)(As + ra * BKP + (cl ^ ((ra >> 1) & 3)) * 8);
            bfr[f] = *(const bf16x8*)(Bs + rb * BKP + (cl ^ ((rb >> 1) & 3)) * 8);
        }
#pragma unroll
        for (int fm = 0; fm < 4; ++fm)
#pragma unroll
            for (int fn = 0; fn < 4; ++fn)
                acc[fm][fn] = __builtin_amdgcn_mfma_f32_16x16x32_bf16(af[fm], bfr[fn], acc[fm][fn], 0, 0, 0);
        __syncthreads();
    }

    const int cr = (lane >> 4) * 4;
    const int cc = lane & 15;
#pragma unroll
    for (int fm = 0; fm < 4; ++fm)
#pragma unroll
        for (int fn = 0; fn < 4; ++fn)
#pragma unroll
            for (int j = 0; j < 4; ++j) {
                int row = row0 + wr * 64 + fm * 16 + cr + j;
                int col = col0 + wc * 64 + fn * 16 + cc;
                Ct[(size_t)row * Rn + col] =
                    __hip_bfloat16(__builtin_bit_cast(__hip_bfloat16_raw, f2bf_bits(acc[fm][fn][j])));
            }
}

// ---------------- sq[i] = sum_r t[i][r]^2 (one wave per row) ----------------
__global__ __launch_bounds__(256)
void sq_kernel(const __hip_bfloat16* __restrict__ T, float* __restrict__ sq) {
    int row  = blockIdx.x * 4 + (threadIdx.x >> 6);
    int lane = threadIdx.x & 63;
    const uint32_t* p = (const uint32_t*)(T + (size_t)row * Rn);
    float s = 0.f;
#pragma unroll
    for (int i = 0; i < 6; ++i) {
        uint32_t u = p[lane + i * 64];
        float lo = __builtin_bit_cast(float, u << 16);
        float hi = __builtin_bit_cast(float, u & 0xffff0000u);
        s = fmaf(lo, lo, s);
        s = fmaf(hi, hi, s);
    }
#pragma unroll
    for (int off = 32; off > 0; off >>= 1) s += __shfl_xor(s, off, 64);
    if (lane == 0) sq[row] = s;
}

// ---------------- symmetric gram, BK=64 + LDS XOR swizzle ----------------
// LDS slot c (0..7 per 128B row) holds logical chunk c ^ (row&7); reads spread
// uniformly over all 8 bank groups (2 rows/group = free).
#define BKG 64
__global__ __launch_bounds__(256, 4)
void gram_sym(const __hip_bfloat16* __restrict__ T, const float* __restrict__ sq,
              float* __restrict__ out) {
    __shared__ __hip_bfloat16 As[128 * BKG];
    __shared__ __hip_bfloat16 Bs[128 * BKG];
    __shared__ float tsc[4][16 * 20];

    const int tid  = threadIdx.x;
    const int lane = tid & 63;
    const int w    = tid >> 6;
    const int wr   = w >> 1, wc = w & 1;

    const int L = blockIdx.x;
    const int b = L & 7;
    int tile_id = L >> 3;               // 0..135
    int ty = 0;
    {
        int rowlen = 16;
        while (tile_id >= rowlen) { tile_id -= rowlen; --rowlen; ++ty; }
    }
    const int tx = ty + tile_id;
    const bool diag = (ty == tx);
    const int row0 = ty * 128;
    const int col0 = tx * 128;

    const __hip_bfloat16* Tb = T + (size_t)b * Sn * Rn;
    const float* sqb = sq + b * Sn;
    float* outb = out + (size_t)b * Sn * Sn;

    f32x4 acc[4][4];
#pragma unroll
    for (int i = 0; i < 4; ++i)
#pragma unroll
        for (int j = 0; j < 4; ++j) acc[i][j] = (f32x4){0.f, 0.f, 0.f, 0.f};

    const int cl = lane >> 4;   // 0..3: 16B chunk within 32-k half
    const int rA = lane & 15;

    for (int k0 = 0; k0 < Rn; k0 += BKG) {
        // stage 128x64 bf16 per matrix = 1024 16B chunks; 4 per thread per matrix
#pragma unroll
        for (int i = 0; i < 4; ++i) {
            int cid = tid + i * 256;        // 0..1023
            int r = cid >> 3;               // row 0..127
            int c = cid & 7;                // LDS slot
            int csrc = c ^ (r & 7);         // logical chunk at this slot
            gload_lds16(Tb + (size_t)(row0 + r) * Rn + k0 + csrc * 8, As + cid * 8);
            if (!diag)
                gload_lds16(Tb + (size_t)(col0 + r) * Rn + k0 + csrc * 8, Bs + cid * 8);
        }
        __syncthreads();

        const __hip_bfloat16* Bsrc = diag ? As : Bs;
#pragma unroll
        for (int ks = 0; ks < 2; ++ks) {    // two k=32 sub-steps of the 64-k tile
            const int clk = cl + ks * 4;    // logical chunk 0..7
            bf16x8 af[4], bfr[4];
#pragma unroll
            for (int f = 0; f < 4; ++f) {
                int ra = wr * 64 + f * 16 + rA;
                int rb = wc * 64 + f * 16 + rA;
                af[f]  = *(const bf16x8*)(As   + ra * BKG + (clk ^ (ra & 7)) * 8);
                bfr[f] = *(const bf16x8*)(Bsrc + rb * BKG + (clk ^ (rb & 7)) * 8);
            }
#pragma unroll
            for (int fm = 0; fm < 4; ++fm)
#pragma unroll
                for (int fn = 0; fn < 4; ++fn)
                    acc[fm][fn] = __builtin_amdgcn_mfma_f32_16x16x32_bf16(af[fm], bfr[fn], acc[fm][fn], 0, 0, 0);
        }
        __syncthreads();
    }

    const int cr = (lane >> 4) * 4;
    const int cc = lane & 15;
    float* sc = tsc[w];

#pragma unroll
    for (int fm = 0; fm < 4; ++fm)
#pragma unroll
        for (int fn = 0; fn < 4; ++fn) {
            const int col = col0 + wc * 64 + fn * 16 + cc;
            const float sqc = sqb[col];
            float v[4];
#pragma unroll
            for (int j = 0; j < 4; ++j) {
                const int row = row0 + wr * 64 + fm * 16 + cr + j;
                v[j] = fmaxf(sqb[row] + sqc - 2.0f * acc[fm][fn][j], 0.0f);
                outb[(size_t)row * Sn + col] = v[j];
            }
            if (!diag) {
#pragma unroll
                for (int j = 0; j < 4; ++j) sc[(cr + j) * 20 + cc] = v[j];
                float4 tv = *(const float4*)(sc + cc * 20 + cr);
#pragma unroll
                for (int j = 0; j < 4; ++j) {
                    const int mrow = col0 + wc * 64 + fn * 16 + cr + j;
                    const int mcol = row0 + wr * 64 + fm * 16 + cc;
                    outb[(size_t)mrow * Sn + mcol] = ((const float*)&tv)[j];
                }
            }
        }
}

extern "C" void kernel_launch(void* const* d_in, const int* in_sizes, int n_in,
                              void* d_out, int out_size, void* d_ws, size_t ws_size,
                              hipStream_t stream) {
    const float* batch = (const float*)d_in[0];   // [8][2048][768] f32
    const float* proj  = (const float*)d_in[1];   // [768][768] f32
    float* out = (float*)d_out;                   // [8][2048][2048] f32

    char* ws = (char*)d_ws;
    __hip_bfloat16* batch_bf = (__hip_bfloat16*)(ws);                    // 25,165,824 B
    __hip_bfloat16* projT    = (__hip_bfloat16*)(ws + 25165824);         //  1,179,648 B
    __hip_bfloat16* t_bf     = (__hip_bfloat16*)(ws + 26345472);         // 25,165,824 B
    float*          sqv      = (float*)(ws + 51511296);                  //     65,536 B

    int n4 = (Mn * Hn) / 4;
    cvt_batch<<<2048, 256, 0, stream>>>((const float4*)batch, (ushort4*)batch_bf, n4);
    cvt_projT<<<(Hn * Rn + 255) / 256, 256, 0, stream>>>(proj, projT);
    gemm_proj<<<dim3(Mn / 128, Rn / 128), 256, 0, stream>>>(batch_bf, projT, t_bf);
    sq_kernel<<<Mn / 4, 256, 0, stream>>>(t_bf, sqv);
    gram_sym<<<8 * 136, 256, 0, stream>>>(t_bf, sqv, out);
}

// Round 4
// 99.324 us; speedup vs baseline: 1.2922x; 1.0330x over previous
//
#include <hip/hip_runtime.h>
#include <hip/hip_bf16.h>
#include <stdint.h>

#define Bn 8
#define Sn 2048
#define Hn 768
#define Rn 768
#define Mn (Bn*Sn)          // 16384

typedef __attribute__((ext_vector_type(8))) __bf16 bf16x8;
typedef __attribute__((ext_vector_type(4))) float f32x4;

__device__ __forceinline__ void gload_lds16(const void* g, void* l) {
    __builtin_amdgcn_global_load_lds(
        (const __attribute__((address_space(1))) uint32_t*)g,
        (__attribute__((address_space(3))) uint32_t*)l,
        16, 0, 0);
}

__device__ __forceinline__ unsigned short f2bf_bits(float f) {
    uint32_t u = __builtin_bit_cast(uint32_t, f);
    u += 0x7fffu + ((u >> 16) & 1u);
    return (unsigned short)(u >> 16);
}

// ---------------- convert + transpose proj: projT[r][h] = bf16(proj[h][r]) ----------------
__global__ void cvt_projT(const float* __restrict__ proj, __hip_bfloat16* __restrict__ projT) {
    int t = blockIdx.x * blockDim.x + threadIdx.x;
    if (t < Hn * Rn) {
        int r = t / Hn;
        int h = t - r * Hn;
        projT[t] = __hip_bfloat16(__builtin_bit_cast(__hip_bfloat16_raw, f2bf_bits(proj[h * Rn + r])));
    }
}

// ---------------- fused projection GEMM ----------------
// t[M][R] = bf16( f32batch[M][H] ) * projT[R][H]^T, with in-kernel f32->bf16 of A
// and fused sq[row] += sum(t_row^2) (rounded-bf16 values, matching old sq_kernel).
// A staged as f32 (128x32, 16 KB, 8 chunk-slots/row, XOR r&7 swizzle per rule 21);
// B staged bf16 (128x32, 8 KB, 4 slots/row, XOR (r>>1)&3).
#define BKP 32
__global__ __launch_bounds__(256, 4)
void gemm_proj_fused(const float* __restrict__ A,            // [Mn][Hn] f32
                     const __hip_bfloat16* __restrict__ Bt,  // [Rn][Hn] bf16
                     __hip_bfloat16* __restrict__ Ct,        // [Mn][Rn] bf16
                     float* __restrict__ sqv) {              // [Mn] f32, pre-zeroed
    __shared__ float Af[128 * BKP];             // 16 KB
    __shared__ __hip_bfloat16 Bs[128 * BKP];    //  8 KB
    const int tid  = threadIdx.x;
    const int lane = tid & 63;
    const int w    = tid >> 6;
    const int wr   = w >> 1, wc = w & 1;
    const int row0 = blockIdx.x * 128;
    const int col0 = blockIdx.y * 128;

    f32x4 acc[4][4];
#pragma unroll
    for (int i = 0; i < 4; ++i)
#pragma unroll
        for (int j = 0; j < 4; ++j) acc[i][j] = (f32x4){0.f, 0.f, 0.f, 0.f};

    const int cl = lane >> 4;     // 0..3: 8-float (two 16B chunks) k-group
    const int rA = lane & 15;

    for (int k0 = 0; k0 < Hn; k0 += BKP) {
        // A: 128 rows x 8 chunks (16B=4 f32) = 1024 chunks, 4/thread
#pragma unroll
        for (int i = 0; i < 4; ++i) {
            int cid = tid + i * 256;
            int r = cid >> 3;
            int c = cid & 7;
            int csrc = c ^ (r & 7);
            gload_lds16(A + (size_t)(row0 + r) * Hn + k0 + csrc * 4, Af + cid * 4);
        }
        // B: 128 rows x 4 chunks (16B=8 bf16) = 512 chunks, 2/thread
#pragma unroll
        for (int i = 0; i < 2; ++i) {
            int c16 = tid + i * 256;
            int r = c16 >> 2;
            int c = c16 & 3;
            int csrc = c ^ ((r >> 1) & 3);
            gload_lds16(Bt + (size_t)(col0 + r) * Hn + k0 + csrc * 8, Bs + c16 * 8);
        }
        __syncthreads();

        bf16x8 af[4], bfr[4];
#pragma unroll
        for (int f = 0; f < 4; ++f) {
            int ra = wr * 64 + f * 16 + rA;
            int rb = wc * 64 + f * 16 + rA;
            f32x4 a0 = *(const f32x4*)(Af + ra * BKP + (((2 * cl + 0) ^ (ra & 7)) * 4));
            f32x4 a1 = *(const f32x4*)(Af + ra * BKP + (((2 * cl + 1) ^ (ra & 7)) * 4));
            union { bf16x8 v; __bf16 e[8]; } u;
#pragma unroll
            for (int p = 0; p < 4; ++p) { u.e[p] = (__bf16)a0[p]; u.e[4 + p] = (__bf16)a1[p]; }
            af[f]  = u.v;
            bfr[f] = *(const bf16x8*)(Bs + rb * BKP + (cl ^ ((rb >> 1) & 3)) * 8);
        }
#pragma unroll
        for (int fm = 0; fm < 4; ++fm)
#pragma unroll
            for (int fn = 0; fn < 4; ++fn)
                acc[fm][fn] = __builtin_amdgcn_mfma_f32_16x16x32_bf16(af[fm], bfr[fn], acc[fm][fn], 0, 0, 0);
        __syncthreads();
    }

    // epilogue: store bf16 t, accumulate row sums of rounded t^2
    const int cr = (lane >> 4) * 4;
    const int cc = lane & 15;
    float rowsum[4][4];
#pragma unroll
    for (int fm = 0; fm < 4; ++fm)
#pragma unroll
        for (int j = 0; j < 4; ++j) rowsum[fm][j] = 0.f;

#pragma unroll
    for (int fm = 0; fm < 4; ++fm)
#pragma unroll
        for (int fn = 0; fn < 4; ++fn)
#pragma unroll
            for (int j = 0; j < 4; ++j) {
                int row = row0 + wr * 64 + fm * 16 + cr + j;
                int col = col0 + wc * 64 + fn * 16 + cc;
                unsigned short bits = f2bf_bits(acc[fm][fn][j]);
                Ct[(size_t)row * Rn + col] =
                    __hip_bfloat16(__builtin_bit_cast(__hip_bfloat16_raw, bits));
                float vr = __builtin_bit_cast(float, (uint32_t)bits << 16);
                rowsum[fm][j] = fmaf(vr, vr, rowsum[fm][j]);
            }

#pragma unroll
    for (int fm = 0; fm < 4; ++fm)
#pragma unroll
        for (int j = 0; j < 4; ++j) {
            float s = rowsum[fm][j];
            s += __shfl_xor(s, 1, 64);
            s += __shfl_xor(s, 2, 64);
            s += __shfl_xor(s, 4, 64);
            s += __shfl_xor(s, 8, 64);
            if (cc == 0)
                atomicAdd(&sqv[row0 + wr * 64 + fm * 16 + cr + j], s);
        }
}

// ---------------- symmetric gram, BK=64 + LDS XOR swizzle (unchanged from R2) ----------------
#define BKG 64
__global__ __launch_bounds__(256, 4)
void gram_sym(const __hip_bfloat16* __restrict__ T, const float* __restrict__ sq,
              float* __restrict__ out) {
    __shared__ __hip_bfloat16 As[128 * BKG];
    __shared__ __hip_bfloat16 Bs[128 * BKG];
    __shared__ float tsc[4][16 * 20];

    const int tid  = threadIdx.x;
    const int lane = tid & 63;
    const int w    = tid >> 6;
    const int wr   = w >> 1, wc = w & 1;

    const int L = blockIdx.x;
    const int b = L & 7;
    int tile_id = L >> 3;               // 0..135
    int ty = 0;
    {
        int rowlen = 16;
        while (tile_id >= rowlen) { tile_id -= rowlen; --rowlen; ++ty; }
    }
    const int tx = ty + tile_id;
    const bool diag = (ty == tx);
    const int row0 = ty * 128;
    const int col0 = tx * 128;

    const __hip_bfloat16* Tb = T + (size_t)b * Sn * Rn;
    const float* sqb = sq + b * Sn;
    float* outb = out + (size_t)b * Sn * Sn;

    f32x4 acc[4][4];
#pragma unroll
    for (int i = 0; i < 4; ++i)
#pragma unroll
        for (int j = 0; j < 4; ++j) acc[i][j] = (f32x4){0.f, 0.f, 0.f, 0.f};

    const int cl = lane >> 4;
    const int rA = lane & 15;

    for (int k0 = 0; k0 < Rn; k0 += BKG) {
#pragma unroll
        for (int i = 0; i < 4; ++i) {
            int cid = tid + i * 256;
            int r = cid >> 3;
            int c = cid & 7;
            int csrc = c ^ (r & 7);
            gload_lds16(Tb + (size_t)(row0 + r) * Rn + k0 + csrc * 8, As + cid * 8);
            if (!diag)
                gload_lds16(Tb + (size_t)(col0 + r) * Rn + k0 + csrc * 8, Bs + cid * 8);
        }
        __syncthreads();

        const __hip_bfloat16* Bsrc = diag ? As : Bs;
#pragma unroll
        for (int ks = 0; ks < 2; ++ks) {
            const int clk = cl + ks * 4;
            bf16x8 af[4], bfr[4];
#pragma unroll
            for (int f = 0; f < 4; ++f) {
                int ra = wr * 64 + f * 16 + rA;
                int rb = wc * 64 + f * 16 + rA;
                af[f]  = *(const bf16x8*)(As   + ra * BKG + (clk ^ (ra & 7)) * 8);
                bfr[f] = *(const bf16x8*)(Bsrc + rb * BKG + (clk ^ (rb & 7)) * 8);
            }
#pragma unroll
            for (int fm = 0; fm < 4; ++fm)
#pragma unroll
                for (int fn = 0; fn < 4; ++fn)
                    acc[fm][fn] = __builtin_amdgcn_mfma_f32_16x16x32_bf16(af[fm], bfr[fn], acc[fm][fn], 0, 0, 0);
        }
        __syncthreads();
    }

    const int cr = (lane >> 4) * 4;
    const int cc = lane & 15;
    float* sc = tsc[w];

#pragma unroll
    for (int fm = 0; fm < 4; ++fm)
#pragma unroll
        for (int fn = 0; fn < 4; ++fn) {
            const int col = col0 + wc * 64 + fn * 16 + cc;
            const float sqc = sqb[col];
            float v[4];
#pragma unroll
            for (int j = 0; j < 4; ++j) {
                const int row = row0 + wr * 64 + fm * 16 + cr + j;
                v[j] = fmaxf(sqb[row] + sqc - 2.0f * acc[fm][fn][j], 0.0f);
                outb[(size_t)row * Sn + col] = v[j];
            }
            if (!diag) {
#pragma unroll
                for (int j = 0; j < 4; ++j) sc[(cr + j) * 20 + cc] = v[j];
                float4 tv = *(const float4*)(sc + cc * 20 + cr);
#pragma unroll
                for (int j = 0; j < 4; ++j) {
                    const int mrow = col0 + wc * 64 + fn * 16 + cr + j;
                    const int mcol = row0 + wr * 64 + fm * 16 + cc;
                    outb[(size_t)mrow * Sn + mcol] = ((const float*)&tv)[j];
                }
            }
        }
}

extern "C" void kernel_launch(void* const* d_in, const int* in_sizes, int n_in,
                              void* d_out, int out_size, void* d_ws, size_t ws_size,
                              hipStream_t stream) {
    const float* batch = (const float*)d_in[0];   // [8][2048][768] f32
    const float* proj  = (const float*)d_in[1];   // [768][768] f32
    float* out = (float*)d_out;                   // [8][2048][2048] f32

    char* ws = (char*)d_ws;
    __hip_bfloat16* projT = (__hip_bfloat16*)(ws);                 //  1,179,648 B
    __hip_bfloat16* t_bf  = (__hip_bfloat16*)(ws + 1179648);       // 25,165,824 B
    float*          sqv   = (float*)(ws + 1179648 + 25165824);     //     65,536 B

    hipMemsetAsync(sqv, 0, Mn * sizeof(float), stream);
    cvt_projT<<<(Hn * Rn + 255) / 256, 256, 0, stream>>>(proj, projT);
    gemm_proj_fused<<<dim3(Mn / 128, Rn / 128), 256, 0, stream>>>(batch, projT, t_bf, sqv);
    gram_sym<<<8 * 136, 256, 0, stream>>>(t_bf, sqv, out);
}